// Round 2
// baseline (4773.379 us; speedup 1.0000x reference)
//
#include <hip/hip_runtime.h>

// Problem: B=64, T=512, I=256, H=512, C=128. LSTM forward (truncation is a
// forward no-op) + final linear projection. fp32 in/out; bf16 MFMA inside.
#define B_ 64
#define T_ 512
#define I_ 256
#define H_ 512
#define C_ 128
#define NW 32                  // worker wgs (target: all on one XCD)
#define NLAUNCH 256
#define HS_BYTES ((size_t)T_ * B_ * H_ * 2)      // 32 MB bf16 h archive
#define FLAGS_BYTES ((size_t)T_ * NW * 4)        // 64 KB
#define GX_OFF (HS_BYTES + FLAGS_BYTES + 1024)
#define GX_FLOATS ((size_t)T_ * 2048 * B_)       // [t][g][b] fp32 x-gates
#define GX_BYTES (GX_FLOATS * 4)                 // 256 MB

typedef __bf16 bf16x8 __attribute__((ext_vector_type(8)));
typedef float f32x4 __attribute__((ext_vector_type(4)));
typedef int i32x4 __attribute__((ext_vector_type(4)));
typedef unsigned long long u64x2 __attribute__((ext_vector_type(2)));

#define MFMA16 __builtin_amdgcn_mfma_f32_16x16x32_bf16

__device__ __forceinline__ bf16x8 cvt8(const float4 a, const float4 b) {
    bf16x8 r;
    r[0] = (__bf16)a.x; r[1] = (__bf16)a.y; r[2] = (__bf16)a.z; r[3] = (__bf16)a.w;
    r[4] = (__bf16)b.x; r[5] = (__bf16)b.y; r[6] = (__bf16)b.z; r[7] = (__bf16)b.w;
    return r;
}
__device__ __forceinline__ float sigm(float x) { return __frcp_rn(1.0f + __expf(-x)); }
__device__ __forceinline__ float tanh_(float x) { return 2.0f * sigm(2.0f * x) - 1.0f; }

// ---------------------------------------------------------------------------
// Gx precompute: Gx[t][g][b] = sum_k x[b,t,k] * W_ih[J(g),k]  (bf16 MFMA,
// f32 accum — identical arithmetic/order to the old in-loop x phase, so the
// recurrent result is bit-identical). Layout [t][g][b] with b contiguous so
// the recurrent kernel's lane loads its C-fragment (4 consecutive b at one g)
// as a single f32x4. g = p*64 + n_local; J(g) = (n&3)*H + p*16 + (n>>2).
// Grid: (t, gblock of 256 g) = 512*8 wgs on all 256 CUs. M=b, N=g, K=I.
// ---------------------------------------------------------------------------
__global__ void __launch_bounds__(512, 1)
gx_kernel(const float* __restrict__ x, const float* __restrict__ W_ih,
          float* __restrict__ gxout)
{
    const int t   = blockIdx.x >> 3;
    const int gb  = blockIdx.x & 7;
    const int tid = threadIdx.x;
    const int w   = tid >> 6;
    const int lane = tid & 63;
    const int l15  = lane & 15;
    const int quad = lane >> 4;

    // stationary B-frags: wave w owns gtiles w*2, w*2+1
    bf16x8 wf[2][8];
#pragma unroll
    for (int s = 0; s < 2; ++s) {
        const int gg = gb * 256 + (w * 2 + s) * 16 + l15;
        const int pw = gg >> 6, nl = gg & 63;
        const int J = (nl & 3) * H_ + pw * 16 + (nl >> 2);
#pragma unroll
        for (int kc = 0; kc < 8; ++kc) {
            const float* sp = W_ih + (size_t)J * I_ + kc * 32 + quad * 8;
            wf[s][kc] = cvt8(((const float4*)sp)[0], ((const float4*)sp)[1]);
        }
    }

    f32x4 acc[2][4];
#pragma unroll
    for (int s = 0; s < 2; ++s)
#pragma unroll
        for (int bt = 0; bt < 4; ++bt) acc[s][bt] = (f32x4){0.f, 0.f, 0.f, 0.f};

#pragma unroll
    for (int kc = 0; kc < 8; ++kc) {
#pragma unroll
        for (int bt = 0; bt < 4; ++bt) {
            const int b = bt * 16 + l15;
            const float* xp = x + ((size_t)b * T_ + t) * I_ + kc * 32 + quad * 8;
            bf16x8 xa = cvt8(((const float4*)xp)[0], ((const float4*)xp)[1]);
            acc[0][bt] = MFMA16(xa, wf[0][kc], acc[0][bt], 0, 0, 0);
            acc[1][bt] = MFMA16(xa, wf[1][kc], acc[1][bt], 0, 0, 0);
        }
    }

#pragma unroll
    for (int s = 0; s < 2; ++s) {
        const int gg = gb * 256 + (w * 2 + s) * 16 + l15;
#pragma unroll
        for (int bt = 0; bt < 4; ++bt) {
            float* dst = gxout + ((size_t)t * 2048 + gg) * 64 + bt * 16 + quad * 4;
            *(f32x4*)dst = acc[s][bt];
        }
    }
}

// ---------------------------------------------------------------------------
// Recurrent kernel, v7 — x phase hoisted out (GX mode).
// v6 post-mortem: lockstep wgs mean the x phase (HBM loads + cvt + 16 MFMAs)
// is pure serial critical path, and 192 stationary weight regs left no room
// to pipeline the 16 h loads. GX mode: acc init = 2 f32x4 loads from Gx,
// prefetched one step ahead (zero latency on path); wi regs freed -> all 16
// h A-frags preloaded before the MFMA block (one L2 latency, not sixteen).
// Flag protocol, census, cell, store path unchanged from v6.
// GX=false is the v6 fallback if the workspace can't hold Gx (256 MB).
// ---------------------------------------------------------------------------
template <bool GX>
__global__ void __launch_bounds__(512, 1)
lstm_kernel_t(const float* __restrict__ x, const float* __restrict__ W_ih,
              const float* __restrict__ W_hh, const float* __restrict__ b_ih,
              const float* __restrict__ b_hh, const float* __restrict__ gx,
              unsigned short* __restrict__ hs, unsigned int* __restrict__ flags,
              unsigned int* __restrict__ claim, unsigned int* __restrict__ slot_xcc)
{
    const int tid  = threadIdx.x;
    const int w    = tid >> 6;
    const int lane = tid & 63;
    const int l15  = lane & 15;
    const int quad = lane >> 4;

    __shared__ int s_slot;
    __shared__ int s_fast;

    unsigned int xcc;
    asm volatile("s_getreg_b32 %0, hwreg(HW_REG_XCC_ID)" : "=s"(xcc));
    xcc &= 0xf;

    if (tid == 0) {
        if (xcc != 0)
            for (int i = 0; i < 32; ++i) __builtin_amdgcn_s_sleep(64);
        s_slot = (int)atomicAdd(claim, 1u);
    }
    __syncthreads();
    const int p = s_slot;
    if (p >= NW) return;                       // non-workers exit

    if (tid == 0)
        __hip_atomic_store(&slot_xcc[p], xcc + 1u, __ATOMIC_RELAXED,
                           __HIP_MEMORY_SCOPE_AGENT);
    {   // census: wait for all 32 claims, check same-XCD
        unsigned int v = 0; int iters = 0;
        while (true) {
            v = __hip_atomic_load(&slot_xcc[lane & (NW - 1)], __ATOMIC_RELAXED,
                                  __HIP_MEMORY_SCOPE_AGENT);
            if (__all(v != 0)) break;
            if (++iters > (1 << 22)) break;
        }
        unsigned int first = __shfl(v, 0);
        int f = __all(v == first) ? 1 : 0;
        if (tid == 0) s_fast = f;
    }
    __syncthreads();
    const bool fast = (s_fast != 0);

    const int mt = w >> 1, npair = w & 1;
    const int arow = mt * 16 + l15;            // A-operand row (batch b)

    __shared__ float gates_lds[64 * 68];       // [b][64 n-cols], pad 68
    __shared__ unsigned short h_tile[64 * 24]; // [b][16 hcols], pad 24 (48 B)

    // stationary W_hh fragments: B[k][n], n = npair*32 + s*16 + l15
    bf16x8 wh[2][16];
#pragma unroll
    for (int s = 0; s < 2; ++s) {
        const int n = npair * 32 + s * 16 + l15;
        const int J = (n & 3) * H_ + p * 16 + (n >> 2);
#pragma unroll
        for (int kc = 0; kc < 16; ++kc) {
            const float* sp = W_hh + (size_t)J * H_ + kc * 32 + quad * 8;
            wh[s][kc] = cvt8(((const float4*)sp)[0], ((const float4*)sp)[1]);
        }
    }
    bf16x8 wi[2][8];                           // only in fallback mode
    if constexpr (!GX) {
#pragma unroll
        for (int s = 0; s < 2; ++s) {
            const int n = npair * 32 + s * 16 + l15;
            const int J = (n & 3) * H_ + p * 16 + (n >> 2);
#pragma unroll
            for (int kc = 0; kc < 8; ++kc) {
                const float* sp = W_ih + (size_t)J * I_ + kc * 32 + quad * 8;
                wi[s][kc] = cvt8(((const float4*)sp)[0], ((const float4*)sp)[1]);
            }
        }
    }

    // elementwise identity: b = lane (tid&63), hcols w and w+8
    float bias[2][4];
#pragma unroll
    for (int half = 0; half < 2; ++half) {
        const int hc = w + half * 8;
#pragma unroll
        for (int g = 0; g < 4; ++g) {
            const int J = g * H_ + p * 16 + hc;
            bias[half][g] = b_ih[J] + b_hh[J];
        }
    }
    float cst[2] = {0.f, 0.f};

    // Gx: per-lane base; frag s at +s*1024 floats, step t at +t*131072 floats
    const float* gxp = nullptr;
    f32x4 pf[2];
    if constexpr (GX) {
        gxp = gx + ((size_t)(p * 64 + npair * 32 + l15)) * 64 + mt * 16 + quad * 4;
        pf[0] = *(const f32x4*)(gxp);
        pf[1] = *(const f32x4*)(gxp + 1024);
    }

    for (int t = 0; t < T_; ++t) {
        f32x4 acc[2];

        if constexpr (GX) {
            // 1) acc init from prefetched Gx; immediately issue next step's
            //    prefetch — it flies during poll + h phase
            acc[0] = pf[0];
            acc[1] = pf[1];
            if (t + 1 < T_) {
                const float* np = gxp + (size_t)(t + 1) * 131072;
                pf[0] = *(const f32x4*)(np);
                pf[1] = *(const f32x4*)(np + 1024);
            }
        } else {
            acc[0] = (f32x4){0.f,0.f,0.f,0.f};
            acc[1] = (f32x4){0.f,0.f,0.f,0.f};
#pragma unroll
            for (int kc = 0; kc < 8; ++kc) {
                const float* xp = x + ((size_t)arow * T_ + t) * I_ + kc * 32 + quad * 8;
                bf16x8 xa = cvt8(((const float4*)xp)[0], ((const float4*)xp)[1]);
                acc[0] = MFMA16(xa, wi[0][kc], acc[0], 0, 0, 0);
                acc[1] = MFMA16(xa, wi[1][kc], acc[1], 0, 0, 0);
            }
        }

        if (t > 0) {
            // 2) single-wave poll of the 32 per-wg flags; other waves park in
            //    the barrier
            const unsigned int* fl = flags + (size_t)(t - 1) * NW;
            if (w == 1) {
                int iters = 0;
                if (fast) {
                    while (true) {
                        unsigned int v;
                        asm volatile("global_load_dword %0, %1, off sc0\n\t"
                                     "s_waitcnt vmcnt(0)"
                                     : "=v"(v) : "v"(fl + (lane & 31)) : "memory");
                        if (__all(v != 0)) break;
                        if (++iters > (1 << 24)) break;   // safety valve
                    }
                } else {
                    while (true) {
                        unsigned int v = __hip_atomic_load(fl + (lane & 31),
                                __ATOMIC_RELAXED, __HIP_MEMORY_SCOPE_AGENT);
                        if (__all(v != 0)) break;
                        if (++iters > (1 << 24)) break;
                    }
                }
            }
            __syncthreads();                 // orders h loads behind the poll
            asm volatile("" ::: "memory");   // no h-load hoisting above poll

            // 3) h A-fragments, 16-deep preload then MFMA block (one L2
            //    latency instead of sixteen); plain cached loads are safe:
            //    first-touch-after-ready (R1-R5 invariant)
            const unsigned short* hrow =
                hs + (size_t)(t - 1) * (B_ * H_) + (size_t)arow * H_;
            if constexpr (GX) {
                bf16x8 a0[8], a1[8];
#pragma unroll
                for (int kc = 0; kc < 8; ++kc)
                    a0[kc] = *(const bf16x8*)(hrow + kc * 32 + quad * 8);
#pragma unroll
                for (int kc = 0; kc < 8; ++kc)
                    a1[kc] = *(const bf16x8*)(hrow + (kc + 8) * 32 + quad * 8);
#pragma unroll
                for (int kc = 0; kc < 8; ++kc) {
                    acc[0] = MFMA16(a0[kc], wh[0][kc], acc[0], 0, 0, 0);
                    acc[1] = MFMA16(a0[kc], wh[1][kc], acc[1], 0, 0, 0);
                }
#pragma unroll
                for (int kc = 0; kc < 8; ++kc) {
                    acc[0] = MFMA16(a1[kc], wh[0][kc + 8], acc[0], 0, 0, 0);
                    acc[1] = MFMA16(a1[kc], wh[1][kc + 8], acc[1], 0, 0, 0);
                }
            } else {
#pragma unroll
                for (int kc = 0; kc < 16; ++kc) {
                    bf16x8 a = *(const bf16x8*)(hrow + kc * 32 + quad * 8);
                    acc[0] = MFMA16(a, wh[0][kc], acc[0], 0, 0, 0);
                    acc[1] = MFMA16(a, wh[1][kc], acc[1], 0, 0, 0);
                }
            }
        }

        // 4) C-frags -> LDS [b][n]
#pragma unroll
        for (int s = 0; s < 2; ++s)
#pragma unroll
            for (int r = 0; r < 4; ++r)
                gates_lds[(mt * 16 + quad * 4 + r) * 68 + npair * 32 + s * 16 + l15]
                    = acc[s][r];
        __syncthreads();

        // 5) cell: thread owns (b=lane, hc=w) and (b=lane, hc=w+8);
        //    4 gates contiguous at n = 4*hc (float4)
#pragma unroll
        for (int half = 0; half < 2; ++half) {
            const int hc = w + half * 8;
            const float4 g4 = *(const float4*)&gates_lds[lane * 68 + hc * 4];
            float i_s = sigm(g4.x + bias[half][0]);
            float f_s = sigm(g4.y + bias[half][1]);
            float g_t = tanh_(g4.z + bias[half][2]);
            float o_s = sigm(g4.w + bias[half][3]);
            cst[half] = f_s * cst[half] + i_s * g_t;
            float h_new = o_s * tanh_(cst[half]);
            h_tile[lane * 24 + hc] = __builtin_bit_cast(unsigned short, (__bf16)h_new);
        }
        __syncthreads();

        // 6) wave 0: gather 32 B/row, store, ACK, raise flag
        if (w == 0) {
            i32x4 v0 = *(const i32x4*)&h_tile[lane * 24];
            i32x4 v1 = *(const i32x4*)&h_tile[lane * 24 + 8];
            unsigned short* dst =
                hs + (size_t)t * (B_ * H_) + (size_t)lane * H_ + p * 16;
            if (fast) {                    // plain stores -> local L2
                ((i32x4*)dst)[0] = v0;
                ((i32x4*)dst)[1] = v1;
            } else {                       // write-through to L3 (sc1)
                const u64x2 a = __builtin_bit_cast(u64x2, v0);
                const u64x2 b = __builtin_bit_cast(u64x2, v1);
                unsigned long long* d64 = (unsigned long long*)dst;
                __hip_atomic_store(d64 + 0, a.x, __ATOMIC_RELAXED, __HIP_MEMORY_SCOPE_AGENT);
                __hip_atomic_store(d64 + 1, a.y, __ATOMIC_RELAXED, __HIP_MEMORY_SCOPE_AGENT);
                __hip_atomic_store(d64 + 2, b.x, __ATOMIC_RELAXED, __HIP_MEMORY_SCOPE_AGENT);
                __hip_atomic_store(d64 + 3, b.y, __ATOMIC_RELAXED, __HIP_MEMORY_SCOPE_AGENT);
            }
            asm volatile("s_waitcnt vmcnt(0)" ::: "memory");
            if (lane == 0) {
                unsigned int* fp = flags + (size_t)t * NW + p;
                if (fast) {
                    unsigned int one = 1;
                    asm volatile("global_store_dword %0, %1, off sc0"
                                 :: "v"(fp), "v"(one) : "memory");
                } else {
                    __hip_atomic_store(fp, 1u, __ATOMIC_RELAXED,
                                       __HIP_MEMORY_SCOPE_AGENT);
                }
            }
        }
    }
}

// ---------------------------------------------------------------------------
// Output projection: out[b,t,c] = hs[t,b,:] @ W_fc[c,:] + b_fc[c]
// 512 wgs (one per t) x 512 threads; W_fc frags stationary in VGPRs.
// ---------------------------------------------------------------------------
__global__ void __launch_bounds__(512, 2)
out_kernel(const unsigned short* __restrict__ hs, const float* __restrict__ W_fc,
           const float* __restrict__ b_fc, float* __restrict__ out)
{
    const int t    = blockIdx.x;
    const int tid  = threadIdx.x;
    const int w    = tid >> 6;      // c-tile 0..7
    const int lane = tid & 63;
    const int l15  = lane & 15;
    const int quad = lane >> 4;

    bf16x8 wf[16];
#pragma unroll
    for (int kc = 0; kc < 16; ++kc) {
        const float* sp = W_fc + (size_t)(w * 16 + l15) * H_ + kc * 32 + quad * 8;
        wf[kc] = cvt8(((const float4*)sp)[0], ((const float4*)sp)[1]);
    }

    f32x4 acc[4];
#pragma unroll
    for (int m = 0; m < 4; ++m) acc[m] = (f32x4){0.f, 0.f, 0.f, 0.f};

    const unsigned short* hsrow = hs + (size_t)t * (B_ * H_);
#pragma unroll
    for (int kc = 0; kc < 16; ++kc) {
#pragma unroll
        for (int m = 0; m < 4; ++m) {
            bf16x8 a = *(const bf16x8*)(hsrow + (size_t)(m * 16 + l15) * H_ +
                                        kc * 32 + quad * 8);
            acc[m] = MFMA16(a, wf[kc], acc[m], 0, 0, 0);
        }
    }

    const int c = w * 16 + l15;
    const float bias = b_fc[c];
#pragma unroll
    for (int m = 0; m < 4; ++m) {
#pragma unroll
        for (int r = 0; r < 4; ++r) {
            int b = m * 16 + quad * 4 + r;
            out[(size_t)b * (T_ * C_) + (size_t)t * C_ + c] = acc[m][r] + bias;
        }
    }
}

extern "C" void kernel_launch(void* const* d_in, const int* in_sizes, int n_in,
                              void* d_out, int out_size, void* d_ws, size_t ws_size,
                              hipStream_t stream)
{
    const float* x    = (const float*)d_in[0];
    const float* W_ih = (const float*)d_in[1];
    const float* W_hh = (const float*)d_in[2];
    const float* b_ih = (const float*)d_in[3];
    const float* b_hh = (const float*)d_in[4];
    const float* W_fc = (const float*)d_in[5];
    const float* b_fc = (const float*)d_in[6];
    float* out = (float*)d_out;

    unsigned short* hs  = (unsigned short*)d_ws;
    unsigned int* flags = (unsigned int*)((char*)d_ws + HS_BYTES);
    unsigned int* claim = (unsigned int*)((char*)d_ws + HS_BYTES + FLAGS_BYTES);
    unsigned int* sxcc  = (unsigned int*)((char*)d_ws + HS_BYTES + FLAGS_BYTES + 64);
    float* gxbuf        = (float*)((char*)d_ws + GX_OFF);

    const bool use_gx = ws_size >= GX_OFF + GX_BYTES;

    // flags/claim/census poisoned 0xAA before every replay -> zero on-stream
    hipMemsetAsync(flags, 0, FLAGS_BYTES + 256, stream);

    if (use_gx) {
        gx_kernel<<<T_ * 8, 512, 0, stream>>>(x, W_ih, gxbuf);
        lstm_kernel_t<true><<<NLAUNCH, 512, 0, stream>>>(x, W_ih, W_hh, b_ih,
                                                         b_hh, gxbuf, hs, flags,
                                                         claim, sxcc);
    } else {
        lstm_kernel_t<false><<<NLAUNCH, 512, 0, stream>>>(x, W_ih, W_hh, b_ih,
                                                          b_hh, gxbuf, hs, flags,
                                                          claim, sxcc);
    }
    out_kernel<<<T_, 512, 0, stream>>>(hs, W_fc, b_fc, out);
}

// Round 7
// 4254.262 us; speedup vs baseline: 1.1220x; 1.1220x over previous
//
#include <hip/hip_runtime.h>

// Problem: B=64, T=512, I=256, H=512, C=128. LSTM forward (truncation is a
// forward no-op) + final linear projection. fp32 in/out; bf16 MFMA inside.
#define B_ 64
#define T_ 512
#define I_ 256
#define H_ 512
#define C_ 128
#define NW 32                  // worker wgs
#define NLAUNCH 256
#define HS_BYTES ((size_t)T_ * B_ * H_ * 2)      // 32 MB bf16 h archive
#define FLAGS_BYTES ((size_t)T_ * NW * 4)        // 64 KB
#define PRE_OFF (HS_BYTES + FLAGS_BYTES + 1024)
#define XB_BYTES ((size_t)B_ * T_ * I_ * 2)      // 16 MB packed bf16 x

typedef __bf16 bf16x8 __attribute__((ext_vector_type(8)));
typedef float f32x4 __attribute__((ext_vector_type(4)));
typedef int i32x4 __attribute__((ext_vector_type(4)));
typedef unsigned long long u64x2 __attribute__((ext_vector_type(2)));

#define MFMA16 __builtin_amdgcn_mfma_f32_16x16x32_bf16

__device__ __forceinline__ bf16x8 cvt8(const float4 a, const float4 b) {
    bf16x8 r;
    r[0] = (__bf16)a.x; r[1] = (__bf16)a.y; r[2] = (__bf16)a.z; r[3] = (__bf16)a.w;
    r[4] = (__bf16)b.x; r[5] = (__bf16)b.y; r[6] = (__bf16)b.z; r[7] = (__bf16)b.w;
    return r;
}
__device__ __forceinline__ float sigm(float x) { return __frcp_rn(1.0f + __expf(-x)); }
__device__ __forceinline__ float tanh_(float x) { return 2.0f * sigm(2.0f * x) - 1.0f; }

// ---------------------------------------------------------------------------
// xb precompute: xb[(t*64+b)*256+k] = bf16(x[b,t,k]) — fragment-ready layout.
// Same cvt8 rounding as the in-loop conversion -> values bit-identical; only
// WHEN the conversion happens changes. Plain stores: kernel-boundary flush
// makes them visible to the next kernel (proven by hs -> out_kernel, R0-R2).
// ---------------------------------------------------------------------------
__global__ void __launch_bounds__(256, 4)
xb_kernel(const float* __restrict__ x, unsigned short* __restrict__ xb)
{
    const size_t cid = (size_t)blockIdx.x * 256 + threadIdx.x;  // bf16x8 chunk
    const size_t e = cid * 8;
    const int k = (int)(e & 255);
    const int btl = (int)(e >> 8);
    const int t = btl >> 6, b = btl & 63;
    const float* sp = x + ((size_t)b * T_ + t) * I_ + k;
    bf16x8 v = cvt8(((const float4*)sp)[0], ((const float4*)sp)[1]);
    *(bf16x8*)(xb + e) = v;
}

// ---------------------------------------------------------------------------
// Recurrent kernel, v11 — CENSUS DELETED; always-L3 handoff.
// Post-mortems R4/R5: every failure since R2 traces to the fast/slow census —
// a consensus over non-coherent per-XCD L2 state that only held under the
// original dispatch timing. Any prior kernel (xb) or placement drift can
// split the decision; a split (some wgs' flags L2-only, others polling L3)
// is livelock -> 0.5s valve per step -> container death.
// v11 runs the R3-proven agent-scope (L3 write-through) protocol
// UNCONDITIONALLY: correct for any wg->XCD placement, any launch order.
//   - h stores: __hip_atomic_store u64, AGENT scope
//   - flag store: __hip_atomic_store AGENT (after vmcnt(0) drains h)
//   - flag poll: __hip_atomic_load AGENT, single wave (w==1), others park
//   - h loads: plain cached (first-touch-after-flag; caches invalidated at
//     dispatch — proven by out_kernel across R0-R2)
// MODE 1: x via packed bf16 xb (drops 16 serial f32 loads + 32 cvts/step;
// xf prefetched one step ahead). MODE 0: v6 in-loop x path (small ws).
// ---------------------------------------------------------------------------
template <int MODE>
__global__ void __launch_bounds__(512, 1)
lstm_kernel_t(const float* __restrict__ x, const float* __restrict__ W_ih,
              const float* __restrict__ W_hh, const float* __restrict__ b_ih,
              const float* __restrict__ b_hh, const unsigned short* __restrict__ xb,
              unsigned short* __restrict__ hs, unsigned int* __restrict__ flags,
              unsigned int* __restrict__ claim)
{
    const int tid  = threadIdx.x;
    const int w    = tid >> 6;
    const int lane = tid & 63;
    const int l15  = lane & 15;
    const int quad = lane >> 4;

    __shared__ int s_slot;

    unsigned int xcc;
    asm volatile("s_getreg_b32 %0, hwreg(HW_REG_XCC_ID)" : "=s"(xcc));
    xcc &= 0xf;

    if (tid == 0) {
        if (xcc != 0)                       // bias workers toward one XCD
            for (int i = 0; i < 32; ++i) __builtin_amdgcn_s_sleep(64);
        s_slot = (int)atomicAdd(claim, 1u);
    }
    __syncthreads();
    const int p = s_slot;
    if (p >= NW) return;                       // non-workers exit

    const int mt = w >> 1, npair = w & 1;
    const int arow = mt * 16 + l15;            // A-operand row (batch b)

    __shared__ float gates_lds[64 * 68];       // [b][64 n-cols], pad 68
    __shared__ unsigned short h_tile[64 * 24]; // [b][16 hcols], pad 24 (48 B)

    // stationary weight fragments: B[k][n], n = npair*32 + s*16 + l15
    bf16x8 wh[2][16], wi[2][8];
#pragma unroll
    for (int s = 0; s < 2; ++s) {
        const int n = npair * 32 + s * 16 + l15;
        const int J = (n & 3) * H_ + p * 16 + (n >> 2);
#pragma unroll
        for (int kc = 0; kc < 16; ++kc) {
            const float* sp = W_hh + (size_t)J * H_ + kc * 32 + quad * 8;
            wh[s][kc] = cvt8(((const float4*)sp)[0], ((const float4*)sp)[1]);
        }
#pragma unroll
        for (int kc = 0; kc < 8; ++kc) {
            const float* sp = W_ih + (size_t)J * I_ + kc * 32 + quad * 8;
            wi[s][kc] = cvt8(((const float4*)sp)[0], ((const float4*)sp)[1]);
        }
    }

    // elementwise identity: b = lane (tid&63), hcols w and w+8
    float bias[2][4];
#pragma unroll
    for (int half = 0; half < 2; ++half) {
        const int hc = w + half * 8;
#pragma unroll
        for (int g = 0; g < 4; ++g) {
            const int J = g * H_ + p * 16 + hc;
            bias[half][g] = b_ih[J] + b_hh[J];
        }
    }
    float cst[2] = {0.f, 0.f};

    bf16x8 xf[8];          // mode 1: step-t packed x frags, prefetched
    if constexpr (MODE == 1) {
        const unsigned short* xp = xb + (size_t)arow * 256;
#pragma unroll
        for (int kc = 0; kc < 8; ++kc)
            xf[kc] = *(const bf16x8*)(xp + kc * 32 + quad * 8);
    }

#pragma unroll 1
    for (int t = 0; t < T_; ++t) {
        f32x4 acc[2] = {{0.f,0.f,0.f,0.f},{0.f,0.f,0.f,0.f}};

        // 1) x contribution — independent of the handoff
        if constexpr (MODE == 1) {
#pragma unroll
            for (int kc = 0; kc < 8; ++kc) {
                acc[0] = MFMA16(xf[kc], wi[0][kc], acc[0], 0, 0, 0);
                acc[1] = MFMA16(xf[kc], wi[1][kc], acc[1], 0, 0, 0);
            }
            if (t + 1 < T_) {   // reload xf for t+1; flies during poll+h+cell
                const unsigned short* xp =
                    xb + ((size_t)(t + 1) * 64 + arow) * 256;
#pragma unroll
                for (int kc = 0; kc < 8; ++kc)
                    xf[kc] = *(const bf16x8*)(xp + kc * 32 + quad * 8);
            }
        } else {
#pragma unroll
            for (int kc = 0; kc < 8; ++kc) {
                const float* xp = x + ((size_t)arow * T_ + t) * I_ + kc * 32 + quad * 8;
                bf16x8 xa = cvt8(((const float4*)xp)[0], ((const float4*)xp)[1]);
                acc[0] = MFMA16(xa, wi[0][kc], acc[0], 0, 0, 0);
                acc[1] = MFMA16(xa, wi[1][kc], acc[1], 0, 0, 0);
            }
        }

        if (t > 0) {
            // 2) single-wave poll (agent scope / L3) of the 32 per-wg flags;
            //    other waves park in the barrier
            const unsigned int* fl = flags + (size_t)(t - 1) * NW;
            if (w == 1) {
                int iters = 0;
                while (true) {
                    unsigned int v = __hip_atomic_load(fl + (lane & 31),
                            __ATOMIC_RELAXED, __HIP_MEMORY_SCOPE_AGENT);
                    if (__all(v != 0)) break;
                    if (++iters > (1 << 24)) break;   // safety valve
                }
            }
            __syncthreads();                 // orders h loads behind the poll
            asm volatile("" ::: "memory");   // no h-load hoisting above poll

            // 3) h A-fragments: plain cached loads (first-touch-after-flag)
            const unsigned short* hrow =
                hs + (size_t)(t - 1) * (B_ * H_) + (size_t)arow * H_;
#pragma unroll
            for (int kc = 0; kc < 16; ++kc) {
                bf16x8 a = *(const bf16x8*)(hrow + kc * 32 + quad * 8);
                acc[0] = MFMA16(a, wh[0][kc], acc[0], 0, 0, 0);
                acc[1] = MFMA16(a, wh[1][kc], acc[1], 0, 0, 0);
            }
        }

        // 4) C-frags -> LDS [b][n]
#pragma unroll
        for (int s = 0; s < 2; ++s)
#pragma unroll
            for (int r = 0; r < 4; ++r)
                gates_lds[(mt * 16 + quad * 4 + r) * 68 + npair * 32 + s * 16 + l15]
                    = acc[s][r];
        __syncthreads();

        // 5) cell: thread owns (b=lane, hc=w) and (b=lane, hc=w+8)
#pragma unroll
        for (int half = 0; half < 2; ++half) {
            const int hc = w + half * 8;
            const float4 g4 = *(const float4*)&gates_lds[lane * 68 + hc * 4];
            float i_s = sigm(g4.x + bias[half][0]);
            float f_s = sigm(g4.y + bias[half][1]);
            float g_t = tanh_(g4.z + bias[half][2]);
            float o_s = sigm(g4.w + bias[half][3]);
            cst[half] = f_s * cst[half] + i_s * g_t;
            float h_new = o_s * tanh_(cst[half]);
            h_tile[lane * 24 + hc] = __builtin_bit_cast(unsigned short, (__bf16)h_new);
        }
        __syncthreads();

        // 6) wave 0: gather 32 B/row, agent-scope store (L3 write-through),
        //    drain, raise flag (agent scope)
        if (w == 0) {
            i32x4 v0 = *(const i32x4*)&h_tile[lane * 24];
            i32x4 v1 = *(const i32x4*)&h_tile[lane * 24 + 8];
            unsigned short* dst =
                hs + (size_t)t * (B_ * H_) + (size_t)lane * H_ + p * 16;
            const u64x2 a = __builtin_bit_cast(u64x2, v0);
            const u64x2 b = __builtin_bit_cast(u64x2, v1);
            unsigned long long* d64 = (unsigned long long*)dst;
            __hip_atomic_store(d64 + 0, a.x, __ATOMIC_RELAXED, __HIP_MEMORY_SCOPE_AGENT);
            __hip_atomic_store(d64 + 1, a.y, __ATOMIC_RELAXED, __HIP_MEMORY_SCOPE_AGENT);
            __hip_atomic_store(d64 + 2, b.x, __ATOMIC_RELAXED, __HIP_MEMORY_SCOPE_AGENT);
            __hip_atomic_store(d64 + 3, b.y, __ATOMIC_RELAXED, __HIP_MEMORY_SCOPE_AGENT);
            asm volatile("s_waitcnt vmcnt(0)" ::: "memory");
            if (lane == 0) {
                unsigned int* fp = flags + (size_t)t * NW + p;
                __hip_atomic_store(fp, 1u, __ATOMIC_RELAXED,
                                   __HIP_MEMORY_SCOPE_AGENT);
            }
        }
    }
}

// ---------------------------------------------------------------------------
// Output projection: out[b,t,c] = hs[t,b,:] @ W_fc[c,:] + b_fc[c]
// 512 wgs (one per t) x 512 threads; W_fc frags stationary in VGPRs.
// ---------------------------------------------------------------------------
__global__ void __launch_bounds__(512, 2)
out_kernel(const unsigned short* __restrict__ hs, const float* __restrict__ W_fc,
           const float* __restrict__ b_fc, float* __restrict__ out)
{
    const int t    = blockIdx.x;
    const int tid  = threadIdx.x;
    const int w    = tid >> 6;      // c-tile 0..7
    const int lane = tid & 63;
    const int l15  = lane & 15;
    const int quad = lane >> 4;

    bf16x8 wf[16];
#pragma unroll
    for (int kc = 0; kc < 16; ++kc) {
        const float* sp = W_fc + (size_t)(w * 16 + l15) * H_ + kc * 32 + quad * 8;
        wf[kc] = cvt8(((const float4*)sp)[0], ((const float4*)sp)[1]);
    }

    f32x4 acc[4];
#pragma unroll
    for (int m = 0; m < 4; ++m) acc[m] = (f32x4){0.f, 0.f, 0.f, 0.f};

    const unsigned short* hsrow = hs + (size_t)t * (B_ * H_);
#pragma unroll
    for (int kc = 0; kc < 16; ++kc) {
#pragma unroll
        for (int m = 0; m < 4; ++m) {
            bf16x8 a = *(const bf16x8*)(hsrow + (size_t)(m * 16 + l15) * H_ +
                                        kc * 32 + quad * 8);
            acc[m] = MFMA16(a, wf[kc], acc[m], 0, 0, 0);
        }
    }

    const int c = w * 16 + l15;
    const float bias = b_fc[c];
#pragma unroll
    for (int m = 0; m < 4; ++m) {
#pragma unroll
        for (int r = 0; r < 4; ++r) {
            int b = m * 16 + quad * 4 + r;
            out[(size_t)b * (T_ * C_) + (size_t)t * C_ + c] = acc[m][r] + bias;
        }
    }
}

extern "C" void kernel_launch(void* const* d_in, const int* in_sizes, int n_in,
                              void* d_out, int out_size, void* d_ws, size_t ws_size,
                              hipStream_t stream)
{
    const float* x    = (const float*)d_in[0];
    const float* W_ih = (const float*)d_in[1];
    const float* W_hh = (const float*)d_in[2];
    const float* b_ih = (const float*)d_in[3];
    const float* b_hh = (const float*)d_in[4];
    const float* W_fc = (const float*)d_in[5];
    const float* b_fc = (const float*)d_in[6];
    float* out = (float*)d_out;

    unsigned short* hs  = (unsigned short*)d_ws;
    unsigned int* flags = (unsigned int*)((char*)d_ws + HS_BYTES);
    unsigned int* claim = (unsigned int*)((char*)d_ws + HS_BYTES + FLAGS_BYTES);
    unsigned short* xb  = (unsigned short*)((char*)d_ws + PRE_OFF);

    // flags/claim zeroed on-stream before every replay
    hipMemsetAsync(flags, 0, FLAGS_BYTES + 512, stream);

    if (ws_size >= PRE_OFF + XB_BYTES) {
        xb_kernel<<<(B_ * T_ * I_ / 8) / 256, 256, 0, stream>>>(x, xb);
        lstm_kernel_t<1><<<NLAUNCH, 512, 0, stream>>>(x, W_ih, W_hh, b_ih, b_hh,
                                                      xb, hs, flags, claim);
    } else {
        lstm_kernel_t<0><<<NLAUNCH, 512, 0, stream>>>(x, W_ih, W_hh, b_ih, b_hh,
                                                      xb, hs, flags, claim);
    }
    out_kernel<<<T_, 512, 0, stream>>>(hs, W_fc, b_fc, out);
}

// Round 8
// 3932.694 us; speedup vs baseline: 1.2138x; 1.0818x over previous
//
#include <hip/hip_runtime.h>

// Problem: B=64, T=512, I=256, H=512, C=128. LSTM forward (truncation is a
// forward no-op) + final linear projection. fp32 in/out; bf16 MFMA inside.
#define B_ 64
#define T_ 512
#define I_ 256
#define H_ 512
#define C_ 128
#define NW 32                  // worker wgs
#define NLAUNCH 256
#define HS_BYTES ((size_t)T_ * B_ * H_ * 2)      // 32 MB bf16 h archive
#define FLAGS_BYTES ((size_t)T_ * NW * 4)        // 64 KB
#define PRE_OFF (HS_BYTES + FLAGS_BYTES + 1024)
#define XB_BYTES ((size_t)B_ * T_ * I_ * 2)      // 16 MB packed bf16 x
#define HIN_LD 520             // h_in row stride (shorts): 512 + 8 pad

typedef __bf16 bf16x8 __attribute__((ext_vector_type(8)));
typedef float f32x4 __attribute__((ext_vector_type(4)));
typedef int i32x4 __attribute__((ext_vector_type(4)));
typedef unsigned long long u64x2 __attribute__((ext_vector_type(2)));

#define MFMA16 __builtin_amdgcn_mfma_f32_16x16x32_bf16

__device__ __forceinline__ bf16x8 cvt8(const float4 a, const float4 b) {
    bf16x8 r;
    r[0] = (__bf16)a.x; r[1] = (__bf16)a.y; r[2] = (__bf16)a.z; r[3] = (__bf16)a.w;
    r[4] = (__bf16)b.x; r[5] = (__bf16)b.y; r[6] = (__bf16)b.z; r[7] = (__bf16)b.w;
    return r;
}
__device__ __forceinline__ float sigm(float x) { return __frcp_rn(1.0f + __expf(-x)); }
__device__ __forceinline__ float tanh_(float x) { return 2.0f * sigm(2.0f * x) - 1.0f; }

// ---------------------------------------------------------------------------
// xb precompute: xb[(t*64+b)*256+k] = bf16(x[b,t,k]) — fragment-ready layout.
// Same cvt8 rounding as the in-loop conversion -> values bit-identical.
// ---------------------------------------------------------------------------
__global__ void __launch_bounds__(256, 4)
xb_kernel(const float* __restrict__ x, unsigned short* __restrict__ xb)
{
    const size_t cid = (size_t)blockIdx.x * 256 + threadIdx.x;  // bf16x8 chunk
    const size_t e = cid * 8;
    const int k = (int)(e & 255);
    const int btl = (int)(e >> 8);
    const int t = btl >> 6, b = btl & 63;
    const float* sp = x + ((size_t)b * T_ + t) * I_ + k;
    bf16x8 v = cvt8(((const float4*)sp)[0], ((const float4*)sp)[1]);
    *(bf16x8*)(xb + e) = v;
}

// ---------------------------------------------------------------------------
// Recurrent kernel, v12 = v11 + LDS-staged h all-gather.
// v11 (proven): census-free always-L3 handoff — agent-scope h/flag stores,
// single-wave agent poll; placement/launch-order robust. 4170 us.
// v12 theory: the remaining bulk is the h fetch — v11's per-wave register
// loads read each hs row TWICE per wg (npair partners) = 128 KB/CU/step of
// L2-miss->L3-hit line requests through one CU's miss pipeline. v12 stages
// hs[t-1] (64 KB) into LDS once, cooperatively (8 waves x 8 rows, coalesced
// 16 B/lane), then serves A-fragments from LDS (padded rows, even banks).
// Same bytes, same MFMA order -> bit-identical result.
// MODE 1: x via packed bf16 xb. MODE 0: v6 in-loop x path (small ws).
// ---------------------------------------------------------------------------
template <int MODE>
__global__ void __launch_bounds__(512, 1)
lstm_kernel_t(const float* __restrict__ x, const float* __restrict__ W_ih,
              const float* __restrict__ W_hh, const float* __restrict__ b_ih,
              const float* __restrict__ b_hh, const unsigned short* __restrict__ xb,
              unsigned short* __restrict__ hs, unsigned int* __restrict__ flags,
              unsigned int* __restrict__ claim)
{
    const int tid  = threadIdx.x;
    const int w    = tid >> 6;
    const int lane = tid & 63;
    const int l15  = lane & 15;
    const int quad = lane >> 4;

    __shared__ int s_slot;

    unsigned int xcc;
    asm volatile("s_getreg_b32 %0, hwreg(HW_REG_XCC_ID)" : "=s"(xcc));
    xcc &= 0xf;

    if (tid == 0) {
        if (xcc != 0)                       // bias workers toward one XCD
            for (int i = 0; i < 32; ++i) __builtin_amdgcn_s_sleep(64);
        s_slot = (int)atomicAdd(claim, 1u);
    }
    __syncthreads();
    const int p = s_slot;
    if (p >= NW) return;                       // non-workers exit

    const int mt = w >> 1, npair = w & 1;
    const int arow = mt * 16 + l15;            // A-operand row (batch b)

    __shared__ float gates_lds[64 * 68];       // [b][64 n-cols], pad 68
    __shared__ unsigned short h_tile[64 * 24]; // [b][16 hcols], pad 24 (48 B)
    __shared__ unsigned short h_in[64 * HIN_LD]; // staged hs[t-1], 65 KB

    // stationary weight fragments: B[k][n], n = npair*32 + s*16 + l15
    bf16x8 wh[2][16], wi[2][8];
#pragma unroll
    for (int s = 0; s < 2; ++s) {
        const int n = npair * 32 + s * 16 + l15;
        const int J = (n & 3) * H_ + p * 16 + (n >> 2);
#pragma unroll
        for (int kc = 0; kc < 16; ++kc) {
            const float* sp = W_hh + (size_t)J * H_ + kc * 32 + quad * 8;
            wh[s][kc] = cvt8(((const float4*)sp)[0], ((const float4*)sp)[1]);
        }
#pragma unroll
        for (int kc = 0; kc < 8; ++kc) {
            const float* sp = W_ih + (size_t)J * I_ + kc * 32 + quad * 8;
            wi[s][kc] = cvt8(((const float4*)sp)[0], ((const float4*)sp)[1]);
        }
    }

    // elementwise identity: b = lane (tid&63), hcols w and w+8
    float bias[2][4];
#pragma unroll
    for (int half = 0; half < 2; ++half) {
        const int hc = w + half * 8;
#pragma unroll
        for (int g = 0; g < 4; ++g) {
            const int J = g * H_ + p * 16 + hc;
            bias[half][g] = b_ih[J] + b_hh[J];
        }
    }
    float cst[2] = {0.f, 0.f};

    bf16x8 xf[8];          // mode 1: step-t packed x frags, prefetched
    if constexpr (MODE == 1) {
        const unsigned short* xp = xb + (size_t)arow * 256;
#pragma unroll
        for (int kc = 0; kc < 8; ++kc)
            xf[kc] = *(const bf16x8*)(xp + kc * 32 + quad * 8);
    }

#pragma unroll 1
    for (int t = 0; t < T_; ++t) {
        f32x4 acc[2] = {{0.f,0.f,0.f,0.f},{0.f,0.f,0.f,0.f}};

        // 1) x contribution — independent of the handoff
        if constexpr (MODE == 1) {
#pragma unroll
            for (int kc = 0; kc < 8; ++kc) {
                acc[0] = MFMA16(xf[kc], wi[0][kc], acc[0], 0, 0, 0);
                acc[1] = MFMA16(xf[kc], wi[1][kc], acc[1], 0, 0, 0);
            }
            if (t + 1 < T_) {   // reload xf for t+1; flies during poll+h+cell
                const unsigned short* xp =
                    xb + ((size_t)(t + 1) * 64 + arow) * 256;
#pragma unroll
                for (int kc = 0; kc < 8; ++kc)
                    xf[kc] = *(const bf16x8*)(xp + kc * 32 + quad * 8);
            }
        } else {
#pragma unroll
            for (int kc = 0; kc < 8; ++kc) {
                const float* xp = x + ((size_t)arow * T_ + t) * I_ + kc * 32 + quad * 8;
                bf16x8 xa = cvt8(((const float4*)xp)[0], ((const float4*)xp)[1]);
                acc[0] = MFMA16(xa, wi[0][kc], acc[0], 0, 0, 0);
                acc[1] = MFMA16(xa, wi[1][kc], acc[1], 0, 0, 0);
            }
        }

        if (t > 0) {
            // 2) single-wave poll (agent scope / L3) of the 32 per-wg flags;
            //    other waves park in the barrier
            const unsigned int* fl = flags + (size_t)(t - 1) * NW;
            if (w == 1) {
                int iters = 0;
                while (true) {
                    unsigned int v = __hip_atomic_load(fl + (lane & 31),
                            __ATOMIC_RELAXED, __HIP_MEMORY_SCOPE_AGENT);
                    if (__all(v != 0)) break;
                    if (++iters > (1 << 24)) break;   // safety valve
                }
            }
            __syncthreads();                 // orders h staging behind the poll
            asm volatile("" ::: "memory");   // no load hoisting above poll

            // 3) stage hs[t-1] (64 KB) into LDS once — each wave 8 rows,
            //    coalesced 16 B/lane (halves v11's duplicated 128 KB/CU);
            //    then A-fragments from LDS (even-bank b128 reads)
            const unsigned short* hbase = hs + (size_t)(t - 1) * (B_ * H_);
            i32x4 tmp[8];
#pragma unroll
            for (int i = 0; i < 8; ++i) {
                const int r = w + i * 8;
                tmp[i] = *(const i32x4*)(hbase + (size_t)r * H_ + lane * 8);
            }
#pragma unroll
            for (int i = 0; i < 8; ++i) {
                const int r = w + i * 8;
                *(i32x4*)&h_in[r * HIN_LD + lane * 8] = tmp[i];
            }
            __syncthreads();

            const unsigned short* hrow_l = h_in + arow * HIN_LD;
#pragma unroll
            for (int kc = 0; kc < 16; ++kc) {
                bf16x8 a = *(const bf16x8*)(hrow_l + kc * 32 + quad * 8);
                acc[0] = MFMA16(a, wh[0][kc], acc[0], 0, 0, 0);
                acc[1] = MFMA16(a, wh[1][kc], acc[1], 0, 0, 0);
            }
        }

        // 4) C-frags -> LDS [b][n]
#pragma unroll
        for (int s = 0; s < 2; ++s)
#pragma unroll
            for (int r = 0; r < 4; ++r)
                gates_lds[(mt * 16 + quad * 4 + r) * 68 + npair * 32 + s * 16 + l15]
                    = acc[s][r];
        __syncthreads();

        // 5) cell: thread owns (b=lane, hc=w) and (b=lane, hc=w+8)
#pragma unroll
        for (int half = 0; half < 2; ++half) {
            const int hc = w + half * 8;
            const float4 g4 = *(const float4*)&gates_lds[lane * 68 + hc * 4];
            float i_s = sigm(g4.x + bias[half][0]);
            float f_s = sigm(g4.y + bias[half][1]);
            float g_t = tanh_(g4.z + bias[half][2]);
            float o_s = sigm(g4.w + bias[half][3]);
            cst[half] = f_s * cst[half] + i_s * g_t;
            float h_new = o_s * tanh_(cst[half]);
            h_tile[lane * 24 + hc] = __builtin_bit_cast(unsigned short, (__bf16)h_new);
        }
        __syncthreads();

        // 6) wave 0: gather 32 B/row, agent-scope store (L3 write-through),
        //    drain, raise flag (agent scope)
        if (w == 0) {
            i32x4 v0 = *(const i32x4*)&h_tile[lane * 24];
            i32x4 v1 = *(const i32x4*)&h_tile[lane * 24 + 8];
            unsigned short* dst =
                hs + (size_t)t * (B_ * H_) + (size_t)lane * H_ + p * 16;
            const u64x2 a = __builtin_bit_cast(u64x2, v0);
            const u64x2 b = __builtin_bit_cast(u64x2, v1);
            unsigned long long* d64 = (unsigned long long*)dst;
            __hip_atomic_store(d64 + 0, a.x, __ATOMIC_RELAXED, __HIP_MEMORY_SCOPE_AGENT);
            __hip_atomic_store(d64 + 1, a.y, __ATOMIC_RELAXED, __HIP_MEMORY_SCOPE_AGENT);
            __hip_atomic_store(d64 + 2, b.x, __ATOMIC_RELAXED, __HIP_MEMORY_SCOPE_AGENT);
            __hip_atomic_store(d64 + 3, b.y, __ATOMIC_RELAXED, __HIP_MEMORY_SCOPE_AGENT);
            asm volatile("s_waitcnt vmcnt(0)" ::: "memory");
            if (lane == 0) {
                unsigned int* fp = flags + (size_t)t * NW + p;
                __hip_atomic_store(fp, 1u, __ATOMIC_RELAXED,
                                   __HIP_MEMORY_SCOPE_AGENT);
            }
        }
    }
}

// ---------------------------------------------------------------------------
// Output projection: out[b,t,c] = hs[t,b,:] @ W_fc[c,:] + b_fc[c]
// 512 wgs (one per t) x 512 threads; W_fc frags stationary in VGPRs.
// ---------------------------------------------------------------------------
__global__ void __launch_bounds__(512, 2)
out_kernel(const unsigned short* __restrict__ hs, const float* __restrict__ W_fc,
           const float* __restrict__ b_fc, float* __restrict__ out)
{
    const int t    = blockIdx.x;
    const int tid  = threadIdx.x;
    const int w    = tid >> 6;      // c-tile 0..7
    const int lane = tid & 63;
    const int l15  = lane & 15;
    const int quad = lane >> 4;

    bf16x8 wf[16];
#pragma unroll
    for (int kc = 0; kc < 16; ++kc) {
        const float* sp = W_fc + (size_t)(w * 16 + l15) * H_ + kc * 32 + quad * 8;
        wf[kc] = cvt8(((const float4*)sp)[0], ((const float4*)sp)[1]);
    }

    f32x4 acc[4];
#pragma unroll
    for (int m = 0; m < 4; ++m) acc[m] = (f32x4){0.f, 0.f, 0.f, 0.f};

    const unsigned short* hsrow = hs + (size_t)t * (B_ * H_);
#pragma unroll
    for (int kc = 0; kc < 16; ++kc) {
#pragma unroll
        for (int m = 0; m < 4; ++m) {
            bf16x8 a = *(const bf16x8*)(hsrow + (size_t)(m * 16 + l15) * H_ +
                                        kc * 32 + quad * 8);
            acc[m] = MFMA16(a, wf[kc], acc[m], 0, 0, 0);
        }
    }

    const int c = w * 16 + l15;
    const float bias = b_fc[c];
#pragma unroll
    for (int m = 0; m < 4; ++m) {
#pragma unroll
        for (int r = 0; r < 4; ++r) {
            int b = m * 16 + quad * 4 + r;
            out[(size_t)b * (T_ * C_) + (size_t)t * C_ + c] = acc[m][r] + bias;
        }
    }
}

extern "C" void kernel_launch(void* const* d_in, const int* in_sizes, int n_in,
                              void* d_out, int out_size, void* d_ws, size_t ws_size,
                              hipStream_t stream)
{
    const float* x    = (const float*)d_in[0];
    const float* W_ih = (const float*)d_in[1];
    const float* W_hh = (const float*)d_in[2];
    const float* b_ih = (const float*)d_in[3];
    const float* b_hh = (const float*)d_in[4];
    const float* W_fc = (const float*)d_in[5];
    const float* b_fc = (const float*)d_in[6];
    float* out = (float*)d_out;

    unsigned short* hs  = (unsigned short*)d_ws;
    unsigned int* flags = (unsigned int*)((char*)d_ws + HS_BYTES);
    unsigned int* claim = (unsigned int*)((char*)d_ws + HS_BYTES + FLAGS_BYTES);
    unsigned short* xb  = (unsigned short*)((char*)d_ws + PRE_OFF);

    // flags/claim zeroed on-stream before every replay
    hipMemsetAsync(flags, 0, FLAGS_BYTES + 512, stream);

    if (ws_size >= PRE_OFF + XB_BYTES) {
        xb_kernel<<<(B_ * T_ * I_ / 8) / 256, 256, 0, stream>>>(x, xb);
        lstm_kernel_t<1><<<NLAUNCH, 512, 0, stream>>>(x, W_ih, W_hh, b_ih, b_hh,
                                                      xb, hs, flags, claim);
    } else {
        lstm_kernel_t<0><<<NLAUNCH, 512, 0, stream>>>(x, W_ih, W_hh, b_ih, b_hh,
                                                      xb, hs, flags, claim);
    }
    out_kernel<<<T_, 512, 0, stream>>>(hs, W_fc, b_fc, out);
}

// Round 10
// 3702.372 us; speedup vs baseline: 1.2893x; 1.0622x over previous
//
#include <hip/hip_runtime.h>

// Problem: B=64, T=512, I=256, H=512, C=128. LSTM forward (truncation is a
// forward no-op) + final linear projection. fp32 in/out; bf16 MFMA inside.
#define B_ 64
#define T_ 512
#define I_ 256
#define H_ 512
#define C_ 128
#define NW 32                  // worker wgs
#define NLAUNCH 256
#define HS_BYTES ((size_t)T_ * B_ * H_ * 2)      // 32 MB bf16 h archive
#define FLAGS_BYTES ((size_t)T_ * NW * 4)        // 64 KB
#define PRE_OFF (HS_BYTES + FLAGS_BYTES + 1024)
#define XB_BYTES ((size_t)B_ * T_ * I_ * 2)      // 16 MB packed bf16 x
#define HIN_LD 520             // h_in row stride (shorts): 512 + 8 pad
#define VALVE (1 << 16)        // fail-fast poll valve (~5 ms; normal wait
                               // is ~200 iters -> 300x margin; a livelock
                               // now degrades to a fast wrong run, not a
                               // container-killing hang)

typedef __bf16 bf16x8 __attribute__((ext_vector_type(8)));
typedef float f32x4 __attribute__((ext_vector_type(4)));
typedef int i32x4 __attribute__((ext_vector_type(4)));
typedef unsigned long long u64x2 __attribute__((ext_vector_type(2)));

#define MFMA16 __builtin_amdgcn_mfma_f32_16x16x32_bf16

__device__ __forceinline__ bf16x8 cvt8(const float4 a, const float4 b) {
    bf16x8 r;
    r[0] = (__bf16)a.x; r[1] = (__bf16)a.y; r[2] = (__bf16)a.z; r[3] = (__bf16)a.w;
    r[4] = (__bf16)b.x; r[5] = (__bf16)b.y; r[6] = (__bf16)b.z; r[7] = (__bf16)b.w;
    return r;
}
__device__ __forceinline__ float sigm(float x) { return __frcp_rn(1.0f + __expf(-x)); }
__device__ __forceinline__ float tanh_(float x) { return 2.0f * sigm(2.0f * x) - 1.0f; }

// ---------------------------------------------------------------------------
// xb precompute: xb[(t*64+b)*256+k] = bf16(x[b,t,k]) — fragment-ready layout.
// Same cvt8 rounding as the in-loop conversion -> values bit-identical.
// ---------------------------------------------------------------------------
__global__ void __launch_bounds__(256, 4)
xb_kernel(const float* __restrict__ x, unsigned short* __restrict__ xb)
{
    const size_t cid = (size_t)blockIdx.x * 256 + threadIdx.x;  // bf16x8 chunk
    const size_t e = cid * 8;
    const int k = (int)(e & 255);
    const int btl = (int)(e >> 8);
    const int t = btl >> 6, b = btl & 63;
    const float* sp = x + ((size_t)b * T_ + t) * I_ + k;
    bf16x8 v = cvt8(((const float4*)sp)[0], ((const float4*)sp)[1]);
    *(bf16x8*)(xb + e) = v;
}

// ---------------------------------------------------------------------------
// Recurrent kernel, v14 = v13 (blocked hs layout) + fail-fast valves.
// v12 post-mortem: WRITE_SIZE showed 4x write amplification — producer's
// agent-scope stores scatter 32 B/lane at 1 KB stride; the drain sits on the
// serial chain before the flag raise. v13/v14 store hs as [t][p][b][16]:
//   - producer wave0 writes ONE contiguous 2 KB block (full lines, fast
//     drain, no amplification)
//   - consumer stage reads ONE contiguous 64 KB region (coalesced 128 B/thr)
//   - out_kernel decodes the same blocked layout
// LDS layout / MFMA order / bytes unchanged -> bit-identical result.
// Protocol unchanged from v11 (census-free always-L3 agent-scope handoff).
// R8 (v13) died without data (infra vs livelock unknown); v14's VALVE=1<<16
// guarantees any livelock surfaces as a fast failing run with diagnostics.
// MODE 1: x via packed bf16 xb. MODE 0: in-loop x path (small ws).
// ---------------------------------------------------------------------------
template <int MODE>
__global__ void __launch_bounds__(512, 1)
lstm_kernel_t(const float* __restrict__ x, const float* __restrict__ W_ih,
              const float* __restrict__ W_hh, const float* __restrict__ b_ih,
              const float* __restrict__ b_hh, const unsigned short* __restrict__ xb,
              unsigned short* __restrict__ hs, unsigned int* __restrict__ flags,
              unsigned int* __restrict__ claim)
{
    const int tid  = threadIdx.x;
    const int w    = tid >> 6;
    const int lane = tid & 63;
    const int l15  = lane & 15;
    const int quad = lane >> 4;

    __shared__ int s_slot;

    unsigned int xcc;
    asm volatile("s_getreg_b32 %0, hwreg(HW_REG_XCC_ID)" : "=s"(xcc));
    xcc &= 0xf;

    if (tid == 0) {
        if (xcc != 0)                       // bias workers toward one XCD
            for (int i = 0; i < 32; ++i) __builtin_amdgcn_s_sleep(64);
        s_slot = (int)atomicAdd(claim, 1u);
    }
    __syncthreads();
    const int p = s_slot;
    if (p >= NW) return;                       // non-workers exit

    const int mt = w >> 1, npair = w & 1;
    const int arow = mt * 16 + l15;            // A-operand row (batch b)

    __shared__ float gates_lds[64 * 68];       // [b][64 n-cols], pad 68
    __shared__ unsigned short h_tile[64 * 24]; // [b][16 hcols], pad 24 (48 B)
    __shared__ unsigned short h_in[64 * HIN_LD]; // staged hs[t-1], 65 KB

    // stationary weight fragments: B[k][n], n = npair*32 + s*16 + l15
    bf16x8 wh[2][16], wi[2][8];
#pragma unroll
    for (int s = 0; s < 2; ++s) {
        const int n = npair * 32 + s * 16 + l15;
        const int J = (n & 3) * H_ + p * 16 + (n >> 2);
#pragma unroll
        for (int kc = 0; kc < 16; ++kc) {
            const float* sp = W_hh + (size_t)J * H_ + kc * 32 + quad * 8;
            wh[s][kc] = cvt8(((const float4*)sp)[0], ((const float4*)sp)[1]);
        }
#pragma unroll
        for (int kc = 0; kc < 8; ++kc) {
            const float* sp = W_ih + (size_t)J * I_ + kc * 32 + quad * 8;
            wi[s][kc] = cvt8(((const float4*)sp)[0], ((const float4*)sp)[1]);
        }
    }

    // elementwise identity: b = lane (tid&63), hcols w and w+8
    float bias[2][4];
#pragma unroll
    for (int half = 0; half < 2; ++half) {
        const int hc = w + half * 8;
#pragma unroll
        for (int g = 0; g < 4; ++g) {
            const int J = g * H_ + p * 16 + hc;
            bias[half][g] = b_ih[J] + b_hh[J];
        }
    }
    float cst[2] = {0.f, 0.f};

    bf16x8 xf[8];          // mode 1: step-t packed x frags, prefetched
    if constexpr (MODE == 1) {
        const unsigned short* xp = xb + (size_t)arow * 256;
#pragma unroll
        for (int kc = 0; kc < 8; ++kc)
            xf[kc] = *(const bf16x8*)(xp + kc * 32 + quad * 8);
    }

#pragma unroll 1
    for (int t = 0; t < T_; ++t) {
        f32x4 acc[2] = {{0.f,0.f,0.f,0.f},{0.f,0.f,0.f,0.f}};

        // 1) x contribution — independent of the handoff
        if constexpr (MODE == 1) {
#pragma unroll
            for (int kc = 0; kc < 8; ++kc) {
                acc[0] = MFMA16(xf[kc], wi[0][kc], acc[0], 0, 0, 0);
                acc[1] = MFMA16(xf[kc], wi[1][kc], acc[1], 0, 0, 0);
            }
            if (t + 1 < T_) {   // reload xf for t+1; flies during poll+h+cell
                const unsigned short* xp =
                    xb + ((size_t)(t + 1) * 64 + arow) * 256;
#pragma unroll
                for (int kc = 0; kc < 8; ++kc)
                    xf[kc] = *(const bf16x8*)(xp + kc * 32 + quad * 8);
            }
        } else {
#pragma unroll
            for (int kc = 0; kc < 8; ++kc) {
                const float* xp = x + ((size_t)arow * T_ + t) * I_ + kc * 32 + quad * 8;
                bf16x8 xa = cvt8(((const float4*)xp)[0], ((const float4*)xp)[1]);
                acc[0] = MFMA16(xa, wi[0][kc], acc[0], 0, 0, 0);
                acc[1] = MFMA16(xa, wi[1][kc], acc[1], 0, 0, 0);
            }
        }

        if (t > 0) {
            // 2) single-wave poll (agent scope / L3) of the 32 per-wg flags;
            //    other waves park in the barrier
            const unsigned int* fl = flags + (size_t)(t - 1) * NW;
            if (w == 1) {
                int iters = 0;
                while (true) {
                    unsigned int v = __hip_atomic_load(fl + (lane & 31),
                            __ATOMIC_RELAXED, __HIP_MEMORY_SCOPE_AGENT);
                    if (__all(v != 0)) break;
                    if (++iters > VALVE) break;       // fail-fast valve
                }
            }
            __syncthreads();                 // orders h staging behind the poll
            asm volatile("" ::: "memory");   // no load hoisting above poll

            // 3) stage hs[t-1] (64 KB, CONTIGUOUS blocked layout) into LDS:
            //    512 threads x 8 x 16 B sequential reads, then decode
            //    (P,b,i) -> h_in[b][P*16+i]. Same bytes as v12.
            const unsigned short* hbase = hs + (size_t)(t - 1) * (B_ * H_);
            i32x4 tmp[8];
#pragma unroll
            for (int c = 0; c < 8; ++c)
                tmp[c] = *(const i32x4*)(hbase + ((size_t)c * 512 + tid) * 8);
#pragma unroll
            for (int c = 0; c < 8; ++c) {
                const int e = (c * 512 + tid) * 8;   // short index in 32K block
                const int P = e >> 10;               // producer block 0..31
                const int b = (e >> 4) & 63;         // batch
                const int i = e & 15;                // 0 or 8
                *(i32x4*)&h_in[b * HIN_LD + P * 16 + i] = tmp[c];
            }
            __syncthreads();

            const unsigned short* hrow_l = h_in + arow * HIN_LD;
#pragma unroll
            for (int kc = 0; kc < 16; ++kc) {
                bf16x8 a = *(const bf16x8*)(hrow_l + kc * 32 + quad * 8);
                acc[0] = MFMA16(a, wh[0][kc], acc[0], 0, 0, 0);
                acc[1] = MFMA16(a, wh[1][kc], acc[1], 0, 0, 0);
            }
        }

        // 4) C-frags -> LDS [b][n]
#pragma unroll
        for (int s = 0; s < 2; ++s)
#pragma unroll
            for (int r = 0; r < 4; ++r)
                gates_lds[(mt * 16 + quad * 4 + r) * 68 + npair * 32 + s * 16 + l15]
                    = acc[s][r];
        __syncthreads();

        // 5) cell: thread owns (b=lane, hc=w) and (b=lane, hc=w+8)
#pragma unroll
        for (int half = 0; half < 2; ++half) {
            const int hc = w + half * 8;
            const float4 g4 = *(const float4*)&gates_lds[lane * 68 + hc * 4];
            float i_s = sigm(g4.x + bias[half][0]);
            float f_s = sigm(g4.y + bias[half][1]);
            float g_t = tanh_(g4.z + bias[half][2]);
            float o_s = sigm(g4.w + bias[half][3]);
            cst[half] = f_s * cst[half] + i_s * g_t;
            float h_new = o_s * tanh_(cst[half]);
            h_tile[lane * 24 + hc] = __builtin_bit_cast(unsigned short, (__bf16)h_new);
        }
        __syncthreads();

        // 6) wave 0: gather 32 B/row from LDS, store ONE contiguous 2 KB
        //    block (hs_blk[t][p][b][16]) agent-scope, drain, raise flag
        if (w == 0) {
            i32x4 v0 = *(const i32x4*)&h_tile[lane * 24];
            i32x4 v1 = *(const i32x4*)&h_tile[lane * 24 + 8];
            unsigned short* dst =
                hs + (size_t)t * (B_ * H_) + (size_t)p * 1024 + lane * 16;
            const u64x2 a = __builtin_bit_cast(u64x2, v0);
            const u64x2 b = __builtin_bit_cast(u64x2, v1);
            unsigned long long* d64 = (unsigned long long*)dst;
            __hip_atomic_store(d64 + 0, a.x, __ATOMIC_RELAXED, __HIP_MEMORY_SCOPE_AGENT);
            __hip_atomic_store(d64 + 1, a.y, __ATOMIC_RELAXED, __HIP_MEMORY_SCOPE_AGENT);
            __hip_atomic_store(d64 + 2, b.x, __ATOMIC_RELAXED, __HIP_MEMORY_SCOPE_AGENT);
            __hip_atomic_store(d64 + 3, b.y, __ATOMIC_RELAXED, __HIP_MEMORY_SCOPE_AGENT);
            asm volatile("s_waitcnt vmcnt(0)" ::: "memory");
            if (lane == 0) {
                unsigned int* fp = flags + (size_t)t * NW + p;
                __hip_atomic_store(fp, 1u, __ATOMIC_RELAXED,
                                   __HIP_MEMORY_SCOPE_AGENT);
            }
        }
    }
}

// ---------------------------------------------------------------------------
// Output projection: out[b,t,c] = hs[t,b,:] @ W_fc[c,:] + b_fc[c]
// hs is in blocked layout [t][P][b][16]: element (b, h=16P+i) at
// t*32768 + P*1024 + b*16 + i. A-frag (b=m*16+l15, k=kc*32+quad*8):
// P = 2kc + (quad>>1), i = (quad&1)*8 -> contiguous bf16x8 within a block.
// ---------------------------------------------------------------------------
__global__ void __launch_bounds__(512, 2)
out_kernel(const unsigned short* __restrict__ hs, const float* __restrict__ W_fc,
           const float* __restrict__ b_fc, float* __restrict__ out)
{
    const int t    = blockIdx.x;
    const int tid  = threadIdx.x;
    const int w    = tid >> 6;      // c-tile 0..7
    const int lane = tid & 63;
    const int l15  = lane & 15;
    const int quad = lane >> 4;

    bf16x8 wf[16];
#pragma unroll
    for (int kc = 0; kc < 16; ++kc) {
        const float* sp = W_fc + (size_t)(w * 16 + l15) * H_ + kc * 32 + quad * 8;
        wf[kc] = cvt8(((const float4*)sp)[0], ((const float4*)sp)[1]);
    }

    f32x4 acc[4];
#pragma unroll
    for (int m = 0; m < 4; ++m) acc[m] = (f32x4){0.f, 0.f, 0.f, 0.f};

    const unsigned short* hsrow = hs + (size_t)t * (B_ * H_);
#pragma unroll
    for (int kc = 0; kc < 16; ++kc) {
#pragma unroll
        for (int m = 0; m < 4; ++m) {
            const int P = 2 * kc + (quad >> 1);
            const int off = (P << 10) + ((m * 16 + l15) << 4) + ((quad & 1) << 3);
            bf16x8 a = *(const bf16x8*)(hsrow + off);
            acc[m] = MFMA16(a, wf[kc], acc[m], 0, 0, 0);
        }
    }

    const int c = w * 16 + l15;
    const float bias = b_fc[c];
#pragma unroll
    for (int m = 0; m < 4; ++m) {
#pragma unroll
        for (int r = 0; r < 4; ++r) {
            int b = m * 16 + quad * 4 + r;
            out[(size_t)b * (T_ * C_) + (size_t)t * C_ + c] = acc[m][r] + bias;
        }
    }
}

extern "C" void kernel_launch(void* const* d_in, const int* in_sizes, int n_in,
                              void* d_out, int out_size, void* d_ws, size_t ws_size,
                              hipStream_t stream)
{
    const float* x    = (const float*)d_in[0];
    const float* W_ih = (const float*)d_in[1];
    const float* W_hh = (const float*)d_in[2];
    const float* b_ih = (const float*)d_in[3];
    const float* b_hh = (const float*)d_in[4];
    const float* W_fc = (const float*)d_in[5];
    const float* b_fc = (const float*)d_in[6];
    float* out = (float*)d_out;

    unsigned short* hs  = (unsigned short*)d_ws;
    unsigned int* flags = (unsigned int*)((char*)d_ws + HS_BYTES);
    unsigned int* claim = (unsigned int*)((char*)d_ws + HS_BYTES + FLAGS_BYTES);
    unsigned short* xb  = (unsigned short*)((char*)d_ws + PRE_OFF);

    // flags/claim zeroed on-stream before every replay
    hipMemsetAsync(flags, 0, FLAGS_BYTES + 512, stream);

    if (ws_size >= PRE_OFF + XB_BYTES) {
        xb_kernel<<<(B_ * T_ * I_ / 8) / 256, 256, 0, stream>>>(x, xb);
        lstm_kernel_t<1><<<NLAUNCH, 512, 0, stream>>>(x, W_ih, W_hh, b_ih, b_hh,
                                                      xb, hs, flags, claim);
    } else {
        lstm_kernel_t<0><<<NLAUNCH, 512, 0, stream>>>(x, W_ih, W_hh, b_ih, b_hh,
                                                      xb, hs, flags, claim);
    }
    out_kernel<<<T_, 512, 0, stream>>>(hs, W_fc, b_fc, out);
}